// Round 7
// baseline (203.822 us; speedup 1.0000x reference)
//
#include <hip/hip_runtime.h>
#include <stdint.h>

typedef unsigned int u32;
typedef unsigned long long u64;

#define NSAMP 32768

// ---------------------------------------------------------------------------
// DIAGNOSTIC ROUND: identical kernel to round 6, launched 3x per call to make
// per-kernel duration K observable via dur_us = H + 3K (H = harness floor,
// round-6 gave H + K = 162.5us) and to force the kernel into rocprof top-5
// (exposing VGPR_Count -> did the 80-load batch actually allocate?).
//
// Fully-fused binarized NAND conv net. Bit 1 <-> +1. y = K - 2*popc(x^w);
// NAND bit (+1) iff popc >= K/2. 8 lanes/sample, 2 oc/lane, shfl_xor merge.
// ---------------------------------------------------------------------------
__device__ __forceinline__ u32 bfe4(u32 v, int off) { return (v >> off) & 15u; }

__global__ __launch_bounds__(256, 4) void nand_net_kernel(
        const float* __restrict__ x,
        const float* __restrict__ w0, const float* __restrict__ w1,
        const float* __restrict__ w2, const float* __restrict__ w3,
        const float* __restrict__ w4, const float* __restrict__ w5,
        float* __restrict__ out) {

    __shared__ u32 lut[256];
    __shared__ u32 Wl[4][16][2];      // layers 1..4, 16 oc, (lo,hi) 64-bit mask
    __shared__ u32 W5m[10];           // layer 5, 16-bit masks
    __shared__ u64 pkLDS[4][8][12];   // [wave][sample][10 used; pad to 12]

    const int tid  = threadIdx.x;
    const int lane = tid & 63;
    const int w    = tid >> 6;

    // ---- prep: binarize weights into LDS forms (~5KB, L2/L3-resident) ----
    {
        u32 nib[16];
        #pragma unroll
        for (int oc = 0; oc < 16; ++oc) {
            float4 f = ((const float4*)w0)[oc];   // [dy*2+dx] = x,y,z,w
            nib[oc] = (f.x > 0.f ? 1u : 0u) | (f.y > 0.f ? 2u : 0u) |
                      (f.z > 0.f ? 4u : 0u) | (f.w > 0.f ? 8u : 0u);
        }
        {
            int e = tid;                           // 256 threads = 256 entries
            u32 na = e & 15u, nb = (u32)e >> 4;    // row0 nibble, row1 nibble
            u32 idxA = (na & 3u) | ((nb & 3u) << 2);   // cols 4X,4X+1
            u32 idxB = (na >> 2) | ((nb >> 2) << 2);   // cols 4X+2,4X+3
            u32 cvA = 0, cvB = 0;
            #pragma unroll
            for (int oc = 0; oc < 16; ++oc) {
                cvA |= (__popc(idxA ^ nib[oc]) >= 2 ? 1u : 0u) << oc;
                cvB |= (__popc(idxB ^ nib[oc]) >= 2 ? 1u : 0u) << oc;
            }
            lut[e] = cvA | (cvB << 16);
        }
        if (tid < 64) {
            const int L = tid >> 4, oc = tid & 15;
            const float* wp = (L == 0) ? w1 : (L == 1) ? w2 : (L == 2) ? w3 : w4;
            wp += oc * 64;
            float4 g[16];
            #pragma unroll
            for (int i = 0; i < 16; ++i) g[i] = ((const float4*)wp)[i];
            // bit (dydx*16 + ci): lo = dy0{dx0,dx1}, hi = dy1{dx0,dx1}
            u32 lo = 0, hi = 0;
            #pragma unroll
            for (int ci = 0; ci < 16; ++ci) {
                lo |= (g[ci].x > 0.f ? 1u : 0u) << ci;
                lo |= (g[ci].y > 0.f ? 1u : 0u) << (16 + ci);
                hi |= (g[ci].z > 0.f ? 1u : 0u) << ci;
                hi |= (g[ci].w > 0.f ? 1u : 0u) << (16 + ci);
            }
            Wl[L][oc][0] = lo; Wl[L][oc][1] = hi;
        }
        if (tid < 10) {
            const float* wp = w5 + tid * 16;
            float4 h0 = ((const float4*)wp)[0], h1 = ((const float4*)wp)[1];
            float4 h2 = ((const float4*)wp)[2], h3 = ((const float4*)wp)[3];
            u32 m = 0;
            m |= (h0.x>0.f?1u:0u)      | (h0.y>0.f?2u:0u)      | (h0.z>0.f?4u:0u)      | (h0.w>0.f?8u:0u);
            m |= (h1.x>0.f?16u:0u)     | (h1.y>0.f?32u:0u)     | (h1.z>0.f?64u:0u)     | (h1.w>0.f?128u:0u);
            m |= (h2.x>0.f?256u:0u)    | (h2.y>0.f?512u:0u)    | (h2.z>0.f?1024u:0u)   | (h2.w>0.f?2048u:0u);
            m |= (h3.x>0.f?4096u:0u)   | (h3.y>0.f?8192u:0u)   | (h3.z>0.f?16384u:0u)  | (h3.w>0.f?32768u:0u);
            W5m[tid] = m;
        }
    }

    // ---- phase 1: ballot-pack this wave's 8 samples (80-load batch) ----
    const int sbase = blockIdx.x * 32 + w * 8;
    {
        const int rhalf = lane >> 5;   // 0: even row of pair, 1: odd row
        const int col   = lane & 31;   // cols 20..31 are junk bits, never read
        const float* xw = x + (size_t)sbase * 784 + rhalf * 28 + col;

        float v[8][10];
        #pragma unroll
        for (int j = 0; j < 8; ++j) {
            const float* xs = xw + (size_t)j * 784;
            #pragma unroll
            for (int k = 0; k < 10; ++k) v[j][k] = xs[k * 56];  // 80 loads
        }
        #pragma unroll
        for (int j = 0; j < 8; ++j) {
            u64 word = 0;
            #pragma unroll
            for (int k = 0; k < 10; ++k) {
                u64 m = __ballot(v[j][k] > 0.0f);
                if (lane == k) word = m;   // u64 k: lo32 = row 2k, hi32 = row 2k+1
            }
            if (lane < 10) pkLDS[w][j][lane] = word;
        }
    }
    __syncthreads();   // lut/Wl/W5m are cross-wave; pkLDS is wave-local

    // ---- phase 2: the net, 8 lanes per sample ----
    const int s8  = lane >> 3;
    const int q   = lane & 7;
    const int ocb = q * 2;            // this lane's 2 output channels
    const int s   = sbase + s8;

    u32 r[20];                        // packed rows 0..19, bit c = col c
    {
        const uint4* qa = (const uint4*)(&pkLDS[w][s8][0]);  // 96B stride, 16B aligned
        #pragma unroll
        for (int i = 0; i < 5; ++i) {
            uint4 v = qa[i];
            r[4*i] = v.x; r[4*i+1] = v.y; r[4*i+2] = v.z; r[4*i+3] = v.w;
        }
    }

    u32 wlo[2], whi[2];
    #define LOADW(L)                                                   \
        _Pragma("unroll")                                              \
        for (int j = 0; j < 2; ++j) {                                  \
            wlo[j] = Wl[L][ocb + j][0]; whi[j] = Wl[L][ocb + j][1];    \
        }

    // 64-bit NAND conv for this lane's 2 ocs; butterfly-merge across the
    // sample's 8 lanes. m biased +32: output bit = bit6 = (mismatch >= 32).
    #define CONV16(dst, LO, HI)                                        \
        {                                                              \
            u32 _lo = (LO), _hi = (HI), _my = 0;                       \
            _Pragma("unroll")                                          \
            for (int j = 0; j < 2; ++j) {                              \
                u32 _m = __popc(_lo ^ wlo[j]) + __popc(_hi ^ whi[j]) + 32u; \
                _my |= ((_m >> 6) & 1u) << (ocb + j);                  \
            }                                                          \
            _my |= (u32)__shfl_xor((int)_my, 1, 64);                   \
            _my |= (u32)__shfl_xor((int)_my, 2, 64);                   \
            dst = _my | (u32)__shfl_xor((int)_my, 4, 64);              \
        }

    // L0 (LUT) + L1 fused: the 5x5 of L1 outputs that feed forward
    u32 cv1[5][5];
    LOADW(0)
    #pragma unroll
    for (int Y = 0; Y < 5; ++Y) {
        #pragma unroll
        for (int X = 0; X < 5; ++X) {
            u32 eA = bfe4(r[4*Y],     4*X) | (bfe4(r[4*Y + 1], 4*X) << 4);
            u32 eB = bfe4(r[4*Y + 2], 4*X) | (bfe4(r[4*Y + 3], 4*X) << 4);
            CONV16(cv1[Y][X], lut[eA], lut[eB])
        }
    }

    // L2: k2 s1, 4x4 needed
    u32 cv2[4][4];
    LOADW(1)
    #pragma unroll
    for (int y = 0; y < 4; ++y) {
        #pragma unroll
        for (int x = 0; x < 4; ++x) {
            CONV16(cv2[y][x],
                   cv1[y][x]     | (cv1[y][x+1]     << 16),
                   cv1[y+1][x]   | (cv1[y+1][x+1]   << 16))
        }
    }

    // L3: k2 s2, 2x2 needed
    u32 cv3[2][2];
    LOADW(2)
    #pragma unroll
    for (int y = 0; y < 2; ++y) {
        #pragma unroll
        for (int x = 0; x < 2; ++x) {
            CONV16(cv3[y][x],
                   cv2[2*y][2*x]   | (cv2[2*y][2*x+1]   << 16),
                   cv2[2*y+1][2*x] | (cv2[2*y+1][2*x+1] << 16))
        }
    }

    // L4: k2 s2 -> 1x1
    u32 cv4;
    LOADW(3)
    CONV16(cv4,
           cv3[0][0] | (cv3[0][1] << 16),
           cv3[1][0] | (cv3[1][1] << 16))

    // L5: 1x1, 10 ocs, K=16: out = -1 iff y>0 iff popc <= 7.
    float* o = out + (size_t)s * 10;
    {
        u32 m = __popc(cv4 ^ W5m[q]);
        o[q] = (m <= 7u) ? -1.0f : 1.0f;
        if (q < 2) {
            u32 m2 = __popc(cv4 ^ W5m[q + 8]);
            o[q + 8] = (m2 <= 7u) ? -1.0f : 1.0f;
        }
    }
    #undef CONV16
    #undef LOADW
}

extern "C" void kernel_launch(void* const* d_in, const int* in_sizes, int n_in,
                              void* d_out, int out_size, void* d_ws, size_t ws_size,
                              hipStream_t stream) {
    const float* x  = (const float*)d_in[0];
    const float* w0 = (const float*)d_in[1];
    const float* w1 = (const float*)d_in[2];
    const float* w2 = (const float*)d_in[3];
    const float* w3 = (const float*)d_in[4];
    const float* w4 = (const float*)d_in[5];
    const float* w5 = (const float*)d_in[6];

    // DIAGNOSTIC: 3 identical, idempotent launches. dur_us = H + 3K lets us
    // solve for per-kernel K against round-6's H + K = 162.5us, and puts the
    // kernel into rocprof's top-5 (VGPR_Count visibility) if K >~ 55us.
    for (int rep = 0; rep < 3; ++rep) {
        nand_net_kernel<<<1024, 256, 0, stream>>>(x, w0, w1, w2, w3, w4, w5,
                                                  (float*)d_out);
    }
}

// Round 8
// 159.755 us; speedup vs baseline: 1.2758x; 1.2758x over previous
//
#include <hip/hip_runtime.h>
#include <stdint.h>

typedef unsigned int u32;
typedef unsigned long long u64;

#define NSAMP 32768

// ---------------------------------------------------------------------------
// Fully-fused binarized NAND conv net (round-6 structure; barrier moved).
// Bit convention: bit 1 <-> +1. For a K-element conv, y = K - 2*popc(x^w);
// NAND output bit (+1) iff y <= 0 iff popc >= K/2.
//
// One block = 256 threads = 4 waves; each wave owns 8 samples (8 lanes per
// sample, each lane computes 2 of 16 output channels; 3-step shfl_xor merge).
// Grid = 1024 blocks -> 4096 waves = 4 waves/SIMD.
//
// __syncthreads() sits AFTER weight-prep (the only cross-wave LDS data) and
// BEFORE pack, so each wave runs pack->net independently: early-finishing
// waves start VALU work while sibling waves' global loads are in flight.
// pkLDS is wave-local; intra-wave LDS RAW ordering is guaranteed by the
// compiler's lgkmcnt tracking (DS ops complete in order).
//
// Measured (r7 diagnostic): K_warm ~= 20.7us; serial floor ~= 17us
// (12-13 mem + 4-5 VALU + prep). Harness floor H ~= 120-140us dominates.
// ---------------------------------------------------------------------------
__device__ __forceinline__ u32 bfe4(u32 v, int off) { return (v >> off) & 15u; }

__global__ __launch_bounds__(256, 4) void nand_net_kernel(
        const float* __restrict__ x,
        const float* __restrict__ w0, const float* __restrict__ w1,
        const float* __restrict__ w2, const float* __restrict__ w3,
        const float* __restrict__ w4, const float* __restrict__ w5,
        float* __restrict__ out) {

    __shared__ u32 lut[256];
    __shared__ u32 Wl[4][16][2];      // layers 1..4, 16 oc, (lo,hi) 64-bit mask
    __shared__ u32 W5m[10];           // layer 5, 16-bit masks
    __shared__ u64 pkLDS[4][8][12];   // [wave][sample][10 used; pad to 12]

    const int tid  = threadIdx.x;
    const int lane = tid & 63;
    const int w    = tid >> 6;

    // ---- prep: binarize weights into LDS forms (~5KB, L2/L3-resident) ----
    {
        u32 nib[16];
        #pragma unroll
        for (int oc = 0; oc < 16; ++oc) {
            float4 f = ((const float4*)w0)[oc];   // [dy*2+dx] = x,y,z,w
            nib[oc] = (f.x > 0.f ? 1u : 0u) | (f.y > 0.f ? 2u : 0u) |
                      (f.z > 0.f ? 4u : 0u) | (f.w > 0.f ? 8u : 0u);
        }
        {
            int e = tid;                           // 256 threads = 256 entries
            u32 na = e & 15u, nb = (u32)e >> 4;    // row0 nibble, row1 nibble
            u32 idxA = (na & 3u) | ((nb & 3u) << 2);   // cols 4X,4X+1
            u32 idxB = (na >> 2) | ((nb >> 2) << 2);   // cols 4X+2,4X+3
            u32 cvA = 0, cvB = 0;
            #pragma unroll
            for (int oc = 0; oc < 16; ++oc) {
                cvA |= (__popc(idxA ^ nib[oc]) >= 2 ? 1u : 0u) << oc;
                cvB |= (__popc(idxB ^ nib[oc]) >= 2 ? 1u : 0u) << oc;
            }
            lut[e] = cvA | (cvB << 16);
        }
        if (tid < 64) {
            const int L = tid >> 4, oc = tid & 15;
            const float* wp = (L == 0) ? w1 : (L == 1) ? w2 : (L == 2) ? w3 : w4;
            wp += oc * 64;
            float4 g[16];
            #pragma unroll
            for (int i = 0; i < 16; ++i) g[i] = ((const float4*)wp)[i];
            // bit (dydx*16 + ci): lo = dy0{dx0,dx1}, hi = dy1{dx0,dx1}
            u32 lo = 0, hi = 0;
            #pragma unroll
            for (int ci = 0; ci < 16; ++ci) {
                lo |= (g[ci].x > 0.f ? 1u : 0u) << ci;
                lo |= (g[ci].y > 0.f ? 1u : 0u) << (16 + ci);
                hi |= (g[ci].z > 0.f ? 1u : 0u) << ci;
                hi |= (g[ci].w > 0.f ? 1u : 0u) << (16 + ci);
            }
            Wl[L][oc][0] = lo; Wl[L][oc][1] = hi;
        }
        if (tid < 10) {
            const float* wp = w5 + tid * 16;
            float4 h0 = ((const float4*)wp)[0], h1 = ((const float4*)wp)[1];
            float4 h2 = ((const float4*)wp)[2], h3 = ((const float4*)wp)[3];
            u32 m = 0;
            m |= (h0.x>0.f?1u:0u)      | (h0.y>0.f?2u:0u)      | (h0.z>0.f?4u:0u)      | (h0.w>0.f?8u:0u);
            m |= (h1.x>0.f?16u:0u)     | (h1.y>0.f?32u:0u)     | (h1.z>0.f?64u:0u)     | (h1.w>0.f?128u:0u);
            m |= (h2.x>0.f?256u:0u)    | (h2.y>0.f?512u:0u)    | (h2.z>0.f?1024u:0u)   | (h2.w>0.f?2048u:0u);
            m |= (h3.x>0.f?4096u:0u)   | (h3.y>0.f?8192u:0u)   | (h3.z>0.f?16384u:0u)  | (h3.w>0.f?32768u:0u);
            W5m[tid] = m;
        }
    }
    __syncthreads();   // prep tables visible to all waves; pack/net below are
                       // wave-independent (no further barriers)

    // ---- phase 1: ballot-pack this wave's 8 samples (80-load batch) ----
    const int sbase = blockIdx.x * 32 + w * 8;
    {
        const int rhalf = lane >> 5;   // 0: even row of pair, 1: odd row
        const int col   = lane & 31;   // cols 20..31 are junk bits, never read
        const float* xw = x + (size_t)sbase * 784 + rhalf * 28 + col;

        float v[8][10];
        #pragma unroll
        for (int j = 0; j < 8; ++j) {
            const float* xs = xw + (size_t)j * 784;
            #pragma unroll
            for (int k = 0; k < 10; ++k) v[j][k] = xs[k * 56];  // 80 loads
        }
        #pragma unroll
        for (int j = 0; j < 8; ++j) {
            u64 word = 0;
            #pragma unroll
            for (int k = 0; k < 10; ++k) {
                u64 m = __ballot(v[j][k] > 0.0f);
                if (lane == k) word = m;   // u64 k: lo32 = row 2k, hi32 = row 2k+1
            }
            if (lane < 10) pkLDS[w][j][lane] = word;
        }
    }
    // no __syncthreads here: pkLDS[w] is written and read by wave w only;
    // intra-wave DS ordering is handled by compiler lgkmcnt waits.

    // ---- phase 2: the net, 8 lanes per sample ----
    const int s8  = lane >> 3;
    const int q   = lane & 7;
    const int ocb = q * 2;            // this lane's 2 output channels
    const int s   = sbase + s8;

    u32 r[20];                        // packed rows 0..19, bit c = col c
    {
        const uint4* qa = (const uint4*)(&pkLDS[w][s8][0]);  // 96B stride, 16B aligned
        #pragma unroll
        for (int i = 0; i < 5; ++i) {
            uint4 v = qa[i];
            r[4*i] = v.x; r[4*i+1] = v.y; r[4*i+2] = v.z; r[4*i+3] = v.w;
        }
    }

    u32 wlo[2], whi[2];
    #define LOADW(L)                                                   \
        _Pragma("unroll")                                              \
        for (int j = 0; j < 2; ++j) {                                  \
            wlo[j] = Wl[L][ocb + j][0]; whi[j] = Wl[L][ocb + j][1];    \
        }

    // 64-bit NAND conv for this lane's 2 ocs; butterfly-merge across the
    // sample's 8 lanes. m biased +32: output bit = bit6 = (mismatch >= 32).
    #define CONV16(dst, LO, HI)                                        \
        {                                                              \
            u32 _lo = (LO), _hi = (HI), _my = 0;                       \
            _Pragma("unroll")                                          \
            for (int j = 0; j < 2; ++j) {                              \
                u32 _m = __popc(_lo ^ wlo[j]) + __popc(_hi ^ whi[j]) + 32u; \
                _my |= ((_m >> 6) & 1u) << (ocb + j);                  \
            }                                                          \
            _my |= (u32)__shfl_xor((int)_my, 1, 64);                   \
            _my |= (u32)__shfl_xor((int)_my, 2, 64);                   \
            dst = _my | (u32)__shfl_xor((int)_my, 4, 64);              \
        }

    // L0 (LUT) + L1 fused: the 5x5 of L1 outputs that feed forward
    u32 cv1[5][5];
    LOADW(0)
    #pragma unroll
    for (int Y = 0; Y < 5; ++Y) {
        #pragma unroll
        for (int X = 0; X < 5; ++X) {
            u32 eA = bfe4(r[4*Y],     4*X) | (bfe4(r[4*Y + 1], 4*X) << 4);
            u32 eB = bfe4(r[4*Y + 2], 4*X) | (bfe4(r[4*Y + 3], 4*X) << 4);
            CONV16(cv1[Y][X], lut[eA], lut[eB])
        }
    }

    // L2: k2 s1, 4x4 needed
    u32 cv2[4][4];
    LOADW(1)
    #pragma unroll
    for (int y = 0; y < 4; ++y) {
        #pragma unroll
        for (int x = 0; x < 4; ++x) {
            CONV16(cv2[y][x],
                   cv1[y][x]     | (cv1[y][x+1]     << 16),
                   cv1[y+1][x]   | (cv1[y+1][x+1]   << 16))
        }
    }

    // L3: k2 s2, 2x2 needed
    u32 cv3[2][2];
    LOADW(2)
    #pragma unroll
    for (int y = 0; y < 2; ++y) {
        #pragma unroll
        for (int x = 0; x < 2; ++x) {
            CONV16(cv3[y][x],
                   cv2[2*y][2*x]   | (cv2[2*y][2*x+1]   << 16),
                   cv2[2*y+1][2*x] | (cv2[2*y+1][2*x+1] << 16))
        }
    }

    // L4: k2 s2 -> 1x1
    u32 cv4;
    LOADW(3)
    CONV16(cv4,
           cv3[0][0] | (cv3[0][1] << 16),
           cv3[1][0] | (cv3[1][1] << 16))

    // L5: 1x1, 10 ocs, K=16: out = -1 iff y>0 iff popc <= 7.
    float* o = out + (size_t)s * 10;
    {
        u32 m = __popc(cv4 ^ W5m[q]);
        o[q] = (m <= 7u) ? -1.0f : 1.0f;
        if (q < 2) {
            u32 m2 = __popc(cv4 ^ W5m[q + 8]);
            o[q + 8] = (m2 <= 7u) ? -1.0f : 1.0f;
        }
    }
    #undef CONV16
    #undef LOADW
}

extern "C" void kernel_launch(void* const* d_in, const int* in_sizes, int n_in,
                              void* d_out, int out_size, void* d_ws, size_t ws_size,
                              hipStream_t stream) {
    const float* x  = (const float*)d_in[0];
    const float* w0 = (const float*)d_in[1];
    const float* w1 = (const float*)d_in[2];
    const float* w2 = (const float*)d_in[3];
    const float* w3 = (const float*)d_in[4];
    const float* w4 = (const float*)d_in[5];
    const float* w5 = (const float*)d_in[6];

    // 1024 blocks x 256 threads = 4096 waves; 32 samples per block
    nand_net_kernel<<<1024, 256, 0, stream>>>(x, w0, w1, w2, w3, w4, w5,
                                              (float*)d_out);
}